// Round 8
// baseline (249.644 us; speedup 1.0000x reference)
//
#include <hip/hip_runtime.h>
#include <hip/hip_bf16.h>

#define B_ 4
#define S_ 2048
#define HD 1024
#define NH 8
#define DK 128
#define WA 67
#define WPAD 96      // cD^T rows: 0..66 data, 67..79 zero, 80 ones (l-col), 81..95 zero

typedef __attribute__((ext_vector_type(8))) short short8;
typedef __attribute__((ext_vector_type(4))) short short4v;
typedef __attribute__((ext_vector_type(4))) float floatx4;

// hardware exp2: one v_exp_f32 (avoid __exp2f - glibc macro collision)
__device__ __forceinline__ float hexp2(float x) { return __builtin_amdgcn_exp2f(x); }

__device__ __forceinline__ short f2bf(float f) {
    union { float f; unsigned u; } c; c.f = f;
    unsigned u = c.u;
    u += 0x7FFF + ((u >> 16) & 1);          // RTNE
    return (short)(u >> 16);
}
__device__ __forceinline__ float bf2f(short s) {
    union { unsigned u; float f; } c; c.u = ((unsigned)(unsigned short)s) << 16;
    return c.f;
}
__device__ __forceinline__ short f2bf_trunc(float f) {
    union { float f; unsigned u; } c; c.f = f;
    return (short)(c.u >> 16);
}

// async 16B global->LDS DMA; LDS dest = wave-uniform base, lane i lands at
// base + i*16. Per-lane global address is free to choose -> XOR swizzle there.
__device__ __forceinline__ void glds16(void* lds, const void* g) {
    __builtin_amdgcn_global_load_lds(
        (const __attribute__((address_space(1))) unsigned*)g,
        (__attribute__((address_space(3))) unsigned*)lds, 16, 0, 0);
}

// db4 filters, pre-reversed for correlation: F[j] = DEC_*[7-j]
__device__ __constant__ float FLO[8] = {
    0.23037781330885523f,  0.7148465705525415f,  0.6308807679295904f,
   -0.02798376941698385f, -0.18703481171888114f, 0.030841381835986965f,
    0.032883011666982945f, -0.010597401784997278f };
__device__ __constant__ float FHI[8] = {
   -0.010597401784997278f, -0.032883011666982945f, 0.030841381835986965f,
    0.18703481171888114f,  -0.02798376941698385f, -0.6308807679295904f,
    0.7148465705525415f,   -0.23037781330885523f };

// ------- fp32 -> bf16 bulk convert, all four inputs in ONE launch ----------
__global__ __launch_bounds__(256) void cvt_all(
    const float* __restrict__ x,  const float* __restrict__ wq,
    const float* __restrict__ wk, const float* __restrict__ wv,
    short* __restrict__ xb, short* __restrict__ wb)
{
    const size_t w_elems = (size_t)HD * HD;
    int blk = blockIdx.x;
    const float* src; short* dst; int lb;
    if (blk < 4096)      { src = x;  dst = xb;               lb = blk; }
    else if (blk < 4608) { src = wq; dst = wb;               lb = blk - 4096; }
    else if (blk < 5120) { src = wk; dst = wb + w_elems;     lb = blk - 4608; }
    else                 { src = wv; dst = wb + 2 * w_elems; lb = blk - 5120; }
    int i = lb * 256 + threadIdx.x;
    const float4* s = (const float4*)src + (size_t)i * 2;
    float4 f0 = s[0], f1 = s[1];
    short8 o;
    o[0] = f2bf(f0.x); o[1] = f2bf(f0.y); o[2] = f2bf(f0.z); o[3] = f2bf(f0.w);
    o[4] = f2bf(f1.x); o[5] = f2bf(f1.y); o[6] = f2bf(f1.z); o[7] = f2bf(f1.w);
    *((short8*)dst + i) = o;
}

// ---------------- QKV projection: y = x @ W^T, 128x128xBK64, XOR-swizzled ---
__global__ __launch_bounds__(256) void qkv_gemm(
    const short* __restrict__ xb, const short* __restrict__ Wb,
    short* __restrict__ Qb, short* __restrict__ Kb, short* __restrict__ Vb)
{
    __shared__ __align__(16) short As[128 * 64];   // 16KB
    __shared__ __align__(16) short Bs[128 * 64];   // 16KB
    const int tid  = threadIdx.x;
    const int wv   = tid >> 6;
    const int lane = tid & 63;
    const int l15  = lane & 15;
    const int quad = lane >> 4;
    const int m0 = blockIdx.x * 128;
    const int n0 = blockIdx.y * 128;
    const int z  = blockIdx.z;
    const short* W = Wb + (size_t)z * HD * HD;
    short* Yb      = (z == 0) ? Qb : (z == 1) ? Kb : Vb;
    // q scale folded with log2(e) so attention softmax can use exp2
    const float scale = (z == 0) ? 0.12751743786072596f : 1.0f;
    const int wm = (wv & 1) * 64;
    const int wn = (wv >> 1) * 64;
    const int srow = lane >> 3;                 // staging: 8 lanes per 128B row
    const int sch  = (lane & 7) ^ (srow & 7);   // swizzled source chunk
    const int rxor = (l15 & 7);                 // fragment-read xor

    floatx4 acc[4][4] = {};
    for (int kk = 0; kk < HD; kk += 64) {
        __syncthreads();
        #pragma unroll
        for (int i = 0; i < 4; ++i) {
            int ti = wv * 4 + i;                // 16 x 1KB issues per tile
            int r  = ti * 8 + srow;
            glds16(As + ti * 512, xb + (size_t)(m0 + r) * HD + kk + sch * 8);
            glds16(Bs + ti * 512, W  + (size_t)(n0 + r) * HD + kk + sch * 8);
        }
        __syncthreads();
        #pragma unroll
        for (int s4 = 0; s4 < 2; ++s4) {
            short8 a[4], b[4];
            #pragma unroll
            for (int t = 0; t < 4; ++t) {
                int ch = (s4 * 4 + quad) ^ rxor;
                a[t] = *(const short8*)&As[(wm + t * 16 + l15) * 64 + ch * 8];
                b[t] = *(const short8*)&Bs[(wn + t * 16 + l15) * 64 + ch * 8];
            }
            #pragma unroll
            for (int mt = 0; mt < 4; ++mt)
                #pragma unroll
                for (int nt = 0; nt < 4; ++nt)
                    acc[mt][nt] = __builtin_amdgcn_mfma_f32_16x16x32_bf16(
                        a[mt], b[nt], acc[mt][nt], 0, 0, 0);
        }
    }
    // C layout: col = l15, row = quad*4+reg. Write bf16 (b,h,s,d).
    #pragma unroll
    for (int mt = 0; mt < 4; ++mt)
        #pragma unroll
        for (int nt = 0; nt < 4; ++nt)
            #pragma unroll
            for (int reg = 0; reg < 4; ++reg) {
                int rg = m0 + wm + mt * 16 + quad * 4 + reg;
                int cg = n0 + wn + nt * 16 + l15;
                int b = rg >> 11, s = rg & 2047;
                int h = cg >> 7,  d = cg & 127;
                Yb[((size_t)(b * NH + h) * S_ + s) * DK + d] = f2bf(acc[mt][nt][reg] * scale);
            }
}

// ---------------- db4 DWT: 64 rows/block x 4 t-chunks; coalesced outA -------
// Also writes the l-ones row (80) and zero rows 67..79, 81..95 of cD^T.
__global__ __launch_bounds__(256) void dwt_kernel(
    const short* __restrict__ Vb, float* __restrict__ outA, short* __restrict__ cdt)
{
    __shared__ float cAs[64][69];        // stride 69 (== 5 mod 32): conflict-free
    const int tid   = threadIdx.x;
    const int rl    = tid & 63;                      // local row
    const int chunk = tid >> 6;                      // t-chunk 0..3
    const int gid = blockIdx.x * 64 + rl;            // global row (b,h,s)
    const int bh  = gid >> 11;
    const int s   = gid & 2047;
    const short* vr = Vb + (size_t)gid * DK;
    auto getv = [&](int i) -> float {
        int k = (i < 6) ? (5 - i) : (i < 134) ? (i - 6) : (261 - i);
        return bf2f(vr[k]);
    };
    const int t0 = chunk * 17;
    const int t1 = (chunk == 3) ? WA : (t0 + 17);
    float win[8];
    #pragma unroll
    for (int j = 0; j < 8; ++j) win[j] = getv(2 * t0 + j);
    for (int t = t0; t < t1; ++t) {
        float lo = 0.f, hi = 0.f;
        #pragma unroll
        for (int j = 0; j < 8; ++j) { lo += win[j] * FLO[j]; hi += win[j] * FHI[j]; }
        cAs[rl][t] = lo;
        cdt[((size_t)bh * WPAD + t) * S_ + s] = f2bf(hi);   // coalesced 2B over s
        #pragma unroll
        for (int j = 0; j < 6; ++j) win[j] = win[j + 2];
        if (t + 1 < t1) { win[6] = getv(2 * t + 8); win[7] = getv(2 * t + 9); }
    }
    if (chunk == 3) {
        #pragma unroll
        for (int w = WA; w < WPAD; ++w)
            cdt[((size_t)bh * WPAD + w) * S_ + s] =
                (w == 80) ? (short)0x3F80 : (short)0;       // ones row 80, else 0
    }
    __syncthreads();
    // coalesced float4 store of the contiguous 64x67 outA region
    float* dst = outA + (size_t)blockIdx.x * (64 * WA);
    for (int i = tid; i < (64 * WA) / 4; i += 256) {
        int f = i * 4;
        float4 v;
        v.x = cAs[(f + 0) / WA][(f + 0) % WA];
        v.y = cAs[(f + 1) / WA][(f + 1) % WA];
        v.z = cAs[(f + 2) / WA][(f + 2) % WA];
        v.w = cAs[(f + 3) / WA][(f + 3) % WA];
        *(float4*)&dst[f] = v;
    }
}

// ---------------- flash attention, split-K=2, unnormalized partials --------
// 128 q-rows/block, each block handles 16 of 32 key-tiles -> grid 1024,
// 3 blocks/CU (44KB LDS). l computed by MFMA via the ones-row at w=80.
// Partials (bf16 O[128][67] + l) written to pbuf; combine kernel sums halves.
__global__ __launch_bounds__(256, 3) void attn_kernel(
    const short* __restrict__ Qb, const short* __restrict__ Kb,
    const short* __restrict__ cdt, short* __restrict__ pbuf)
{
    __shared__ __align__(16) short Ks[64 * 128];      // 16KB, 16 chunks/row
    __shared__ __align__(16) short Ds[WPAD * 64];     // 12KB, 8 chunks/row
    __shared__ __align__(16) short Pt[8 * 1024];      // 16KB, wave-private P
    const int tid  = threadIdx.x;
    const int wv   = tid >> 6;
    const int lane = tid & 63;
    const int l15  = lane & 15;
    const int quad = lane >> 4;
    const int qt   = blockIdx.x >> 1;    // 0..15 (128 q-rows each)
    const int half = blockIdx.x & 1;     // key-range half
    const int bh = blockIdx.y;           // 0..31
    const int rxor = l15 & 7;

    // Q fragments from global, once. Lane layout = row l15, k = quad*8+j
    // (identical for A- and B-operands, so they serve as B in S^T = K Q^T).
    short8 aq[2][4];
    #pragma unroll
    for (int n = 0; n < 2; ++n) {
        const short* qrow =
            Qb + ((size_t)bh * S_ + qt * 128 + wv * 32 + n * 16 + l15) * DK;
        #pragma unroll
        for (int s4 = 0; s4 < 4; ++s4)
            aq[n][s4] = *(const short8*)(qrow + s4 * 32 + quad * 8);
    }

    floatx4 O[2][6] = {};                // col w=80 (j=5) accumulates l

    const short* kbase = Kb + (size_t)bh * S_ * DK;
    const int krow = lane >> 4;                    // K staging: 4 rows/issue
    const int kch  = (lane & 15);
    const int drow = lane >> 3;                    // D staging: 8 rows/issue
    const int dch  = (lane & 7) ^ (drow & 7);
    short* ptw = Pt + wv * 2048;                   // this wave's P (2 tiles)

    for (int kt = half * 16; kt < half * 16 + 16; ++kt) {
        __syncthreads();                 // prior iter done reading Ks/Ds
        #pragma unroll
        for (int i = 0; i < 4; ++i) {    // K tile: 64 rows x 256B, 16 issues
            int ti = wv * 4 + i;
            int r  = ti * 4 + krow;
            int ch = kch ^ (r & 7);
            glds16(Ks + ti * 512, kbase + ((size_t)kt * 64 + r) * DK + ch * 8);
        }
        #pragma unroll
        for (int i = 0; i < 3; ++i) {    // D tile: 96 rows x 128B, 12 issues
            int t = wv + i * 4;
            int r = t * 8 + drow;
            glds16(Ds + t * 512,
                   cdt + ((size_t)bh * WPAD + r) * S_ + kt * 64 + dch * 8);
        }
        __syncthreads();                 // vmcnt drained -> tiles ready

        // S^T = K Q^T : C col=l15=q-row, row=quad*4+reg=key
        floatx4 sc[2][4] = {};
        #pragma unroll
        for (int s4 = 0; s4 < 4; ++s4) {
            short8 kf[4];
            #pragma unroll
            for (int mt = 0; mt < 4; ++mt) {
                int ch = (s4 * 4 + quad) ^ rxor;
                kf[mt] = *(const short8*)&Ks[(mt * 16 + l15) * 128 + ch * 8];
            }
            #pragma unroll
            for (int n = 0; n < 2; ++n)
                #pragma unroll
                for (int mt = 0; mt < 4; ++mt)
                    sc[n][mt] = __builtin_amdgcn_mfma_f32_16x16x32_bf16(
                        kf[mt], aq[n][s4], sc[n][mt], 0, 0, 0);
        }
        // p = 2^s; 4 regs = 4 consecutive keys of q-row n*16+l15 -> b64 pack
        #pragma unroll
        for (int n = 0; n < 2; ++n) {
            #pragma unroll
            for (int mt = 0; mt < 4; ++mt) {
                short4v pk;
                #pragma unroll
                for (int reg = 0; reg < 4; ++reg)
                    pk[reg] = f2bf_trunc(hexp2(sc[n][mt][reg]));
                int ch = (mt * 2 + (quad >> 1)) ^ rxor;
                *(short4v*)&ptw[n * 1024 + l15 * 64 + ch * 8 + (quad & 1) * 4] = pk;
            }
        }
        // O += P @ cD ; j=5 tile's col 80 (ones row) accumulates l for free
        short8 ap[2][2];
        #pragma unroll
        for (int mt = 0; mt < 2; ++mt)
            #pragma unroll
            for (int ks = 0; ks < 2; ++ks) {
                int ch = (ks * 4 + quad) ^ rxor;
                ap[mt][ks] = *(const short8*)&ptw[mt * 1024 + l15 * 64 + ch * 8];
            }
        #pragma unroll
        for (int j = 0; j < 6; ++j) {
            #pragma unroll
            for (int ks = 0; ks < 2; ++ks) {
                int ch = (ks * 4 + quad) ^ rxor;
                short8 bd = *(const short8*)&Ds[(j * 16 + l15) * 64 + ch * 8];
                #pragma unroll
                for (int mt = 0; mt < 2; ++mt)
                    O[mt][j] = __builtin_amdgcn_mfma_f32_16x16x32_bf16(
                        ap[mt][ks], bd, O[mt][j], 0, 0, 0);
            }
        }
    }
    // store unnormalized partial (bf16): [half][bh][qrow][0..66]=O, [67]=l
    short* pb = pbuf + ((size_t)(half * 32 + bh) * S_) * 68;
    #pragma unroll
    for (int mt = 0; mt < 2; ++mt)
        #pragma unroll
        for (int j = 0; j < 6; ++j) {
            int w = j * 16 + l15;
            #pragma unroll
            for (int reg = 0; reg < 4; ++reg) {
                int qrow = qt * 128 + wv * 32 + mt * 16 + quad * 4 + reg;
                if (w < WA)
                    pb[(size_t)qrow * 68 + w] = f2bf(O[mt][j][reg]);
                else if (w == 80)                       // l lives in col 80
                    pb[(size_t)qrow * 68 + 67] = f2bf(O[mt][j][reg]);
            }
        }
}

// ---------------- combine: out1 = (Oa+Ob) / (la+lb) -------------------------
__global__ __launch_bounds__(256) void combine_kernel(
    const short* __restrict__ pbuf, float* __restrict__ out1)
{
    unsigned idx = blockIdx.x * 256 + threadIdx.x;    // < 32*2048*67
    unsigned bhq = idx / 67;
    unsigned w   = idx - bhq * 67;
    unsigned bh  = bhq >> 11, q = bhq & 2047;
    const short* a = pbuf + (size_t)bh * S_ * 68 + (size_t)q * 68;
    const short* c = a + (size_t)32 * S_ * 68;
    float num = bf2f(a[w]) + bf2f(c[w]);
    float den = bf2f(a[67]) + bf2f(c[67]);
    unsigned b = bh >> 3, h = bh & 7;
    out1[((size_t)(b * S_ + q)) * (NH * WA) + h * WA + w] = num / den;
}

extern "C" void kernel_launch(void* const* d_in, const int* in_sizes, int n_in,
                              void* d_out, int out_size, void* d_ws, size_t ws_size,
                              hipStream_t stream)
{
    const float* x  = (const float*)d_in[0];
    const float* Wq = (const float*)d_in[1];
    const float* Wk = (const float*)d_in[2];
    const float* Wv = (const float*)d_in[3];
    float* out = (float*)d_out;

    const size_t x_elems   = (size_t)B_ * S_ * HD;           // 8,388,608
    const size_t w_elems   = (size_t)HD * HD;                // 1,048,576
    const size_t qkv_elems = (size_t)B_ * NH * S_ * DK;      // 8,388,608
    short* xb  = (short*)d_ws;
    short* Wb  = xb + x_elems;                               // 3 concatenated
    short* Qb  = Wb + 3 * w_elems;
    short* Kb  = Qb + qkv_elems;
    short* Vb  = Kb + qkv_elems;
    short* cdt = Vb + qkv_elems;                             // (b,h,w=96,s) bf16
    // partial buffer reuses the xb/Wb region (dead after qkv_gemm):
    // 2 halves x 32 bh x 2048 q x 68 bf16 = 17.8MB < 23.1MB
    short* pbuf = xb;
    float* out1 = out;                                       // (B,S,536)
    float* out2 = out + (size_t)B_ * S_ * NH * WA;           // (B,H,S,67)

    cvt_all<<<dim3(5632), 256, 0, stream>>>(x, Wq, Wk, Wv, xb, Wb);
    qkv_gemm<<<dim3(64, 8, 3), 256, 0, stream>>>(xb, Wb, Qb, Kb, Vb);
    dwt_kernel<<<dim3(1024), 256, 0, stream>>>(Vb, out2, cdt);
    attn_kernel<<<dim3(32, 32), 256, 0, stream>>>(Qb, Kb, cdt, pbuf);
    combine_kernel<<<dim3(17152), 256, 0, stream>>>(pbuf, out1);
}

// Round 9
// 229.654 us; speedup vs baseline: 1.0870x; 1.0870x over previous
//
#include <hip/hip_runtime.h>
#include <hip/hip_bf16.h>

#define B_ 4
#define S_ 2048
#define HD 1024
#define NH 8
#define DK 128
#define WA 67
#define WPAD 80      // cD^T rows: 0..66 data, 67 = ones (l-column), 68..79 zero

typedef __attribute__((ext_vector_type(8))) short short8;
typedef __attribute__((ext_vector_type(4))) short short4v;
typedef __attribute__((ext_vector_type(4))) float floatx4;

// hardware exp2: one v_exp_f32 (avoid __exp2f - glibc macro collision)
__device__ __forceinline__ float hexp2(float x) { return __builtin_amdgcn_exp2f(x); }

__device__ __forceinline__ short f2bf(float f) {
    union { float f; unsigned u; } c; c.f = f;
    unsigned u = c.u;
    u += 0x7FFF + ((u >> 16) & 1);          // RTNE
    return (short)(u >> 16);
}
__device__ __forceinline__ float bf2f(short s) {
    union { unsigned u; float f; } c; c.u = ((unsigned)(unsigned short)s) << 16;
    return c.f;
}
__device__ __forceinline__ short f2bf_trunc(float f) {
    union { float f; unsigned u; } c; c.f = f;
    return (short)(c.u >> 16);
}

// async 16B global->LDS DMA; LDS dest = wave-uniform base, lane i lands at
// base + i*16. Per-lane global address is free to choose -> XOR swizzle there.
__device__ __forceinline__ void glds16(void* lds, const void* g) {
    __builtin_amdgcn_global_load_lds(
        (const __attribute__((address_space(1))) unsigned*)g,
        (__attribute__((address_space(3))) unsigned*)lds, 16, 0, 0);
}

// db4 filters, pre-reversed for correlation: F[j] = DEC_*[7-j]
__device__ __constant__ float FLO[8] = {
    0.23037781330885523f,  0.7148465705525415f,  0.6308807679295904f,
   -0.02798376941698385f, -0.18703481171888114f, 0.030841381835986965f,
    0.032883011666982945f, -0.010597401784997278f };
__device__ __constant__ float FHI[8] = {
   -0.010597401784997278f, -0.032883011666982945f, 0.030841381835986965f,
    0.18703481171888114f,  -0.02798376941698385f, -0.6308807679295904f,
    0.7148465705525415f,   -0.23037781330885523f };

// ------- fp32 -> bf16 bulk convert, all four inputs in ONE launch ----------
__global__ __launch_bounds__(256) void cvt_all(
    const float* __restrict__ x,  const float* __restrict__ wq,
    const float* __restrict__ wk, const float* __restrict__ wv,
    short* __restrict__ xb, short* __restrict__ wb)
{
    const size_t w_elems = (size_t)HD * HD;
    int blk = blockIdx.x;
    const float* src; short* dst; int lb;
    if (blk < 4096)      { src = x;  dst = xb;               lb = blk; }
    else if (blk < 4608) { src = wq; dst = wb;               lb = blk - 4096; }
    else if (blk < 5120) { src = wk; dst = wb + w_elems;     lb = blk - 4608; }
    else                 { src = wv; dst = wb + 2 * w_elems; lb = blk - 5120; }
    int i = lb * 256 + threadIdx.x;
    const float4* s = (const float4*)src + (size_t)i * 2;
    float4 f0 = s[0], f1 = s[1];
    short8 o;
    o[0] = f2bf(f0.x); o[1] = f2bf(f0.y); o[2] = f2bf(f0.z); o[3] = f2bf(f0.w);
    o[4] = f2bf(f1.x); o[5] = f2bf(f1.y); o[6] = f2bf(f1.z); o[7] = f2bf(f1.w);
    *((short8*)dst + i) = o;
}

// ------- QKV projection + fused DWT on the V path ---------------------------
// 128x128xBK64 m97-style GEMM. For z==2 (V), the n-block is exactly one
// head's full d-range, so the epilogue stages the V tile in LDS (union'd
// over As/Bs; stride 134 shorts -> gcd(67,32)=1, conflict-free column reads)
// and computes the db4 DWT in-block: cA -> out2 directly, cD^T (+ ones row
// 67, zero rows 68..79) -> cdt. Kills the separate dwt kernel and the
// 16MB Vb write + 16MB re-read.
__global__ __launch_bounds__(256) void qkv_gemm(
    const short* __restrict__ xb, const short* __restrict__ Wb,
    short* __restrict__ Qb, short* __restrict__ Kb,
    float* __restrict__ outA, short* __restrict__ cdt)
{
    __shared__ __align__(16) short smem[128 * 134];   // 34.3KB
    short* As = smem;                  // [128][64] during K-loop
    short* Bs = smem + 128 * 64;       // [128][64] during K-loop
    short* Cs = smem;                  // [128][134] V tile (z==2 epilogue)
    const int tid  = threadIdx.x;
    const int wv   = tid >> 6;
    const int lane = tid & 63;
    const int l15  = lane & 15;
    const int quad = lane >> 4;
    const int m0 = blockIdx.x * 128;
    const int n0 = blockIdx.y * 128;
    const int z  = blockIdx.z;
    const short* W = Wb + (size_t)z * HD * HD;
    // q scale folded with log2(e) so attention softmax can use exp2
    const float scale = (z == 0) ? 0.12751743786072596f : 1.0f;
    const int wm = (wv & 1) * 64;
    const int wn = (wv >> 1) * 64;
    const int srow = lane >> 3;                 // staging: 8 lanes per 128B row
    const int sch  = (lane & 7) ^ (srow & 7);   // swizzled source chunk
    const int rxor = (l15 & 7);                 // fragment-read xor

    floatx4 acc[4][4] = {};
    for (int kk = 0; kk < HD; kk += 64) {
        __syncthreads();
        #pragma unroll
        for (int i = 0; i < 4; ++i) {
            int ti = wv * 4 + i;                // 16 x 1KB issues per tile
            int r  = ti * 8 + srow;
            glds16(As + ti * 512, xb + (size_t)(m0 + r) * HD + kk + sch * 8);
            glds16(Bs + ti * 512, W  + (size_t)(n0 + r) * HD + kk + sch * 8);
        }
        __syncthreads();
        #pragma unroll
        for (int s4 = 0; s4 < 2; ++s4) {
            short8 a[4], b[4];
            #pragma unroll
            for (int t = 0; t < 4; ++t) {
                int ch = (s4 * 4 + quad) ^ rxor;
                a[t] = *(const short8*)&As[(wm + t * 16 + l15) * 64 + ch * 8];
                b[t] = *(const short8*)&Bs[(wn + t * 16 + l15) * 64 + ch * 8];
            }
            #pragma unroll
            for (int mt = 0; mt < 4; ++mt)
                #pragma unroll
                for (int nt = 0; nt < 4; ++nt)
                    acc[mt][nt] = __builtin_amdgcn_mfma_f32_16x16x32_bf16(
                        a[mt], b[nt], acc[mt][nt], 0, 0, 0);
        }
    }
    // C layout: col = l15, row = quad*4+reg.
    if (z != 2) {
        short* Yb = (z == 0) ? Qb : Kb;
        #pragma unroll
        for (int mt = 0; mt < 4; ++mt)
            #pragma unroll
            for (int nt = 0; nt < 4; ++nt)
                #pragma unroll
                for (int reg = 0; reg < 4; ++reg) {
                    int rg = m0 + wm + mt * 16 + quad * 4 + reg;
                    int cg = n0 + wn + nt * 16 + l15;
                    int b = rg >> 11, s = rg & 2047;
                    int h = cg >> 7,  d = cg & 127;
                    Yb[((size_t)(b * NH + h) * S_ + s) * DK + d] =
                        f2bf(acc[mt][nt][reg] * scale);
                }
        return;
    }
    // ---- z==2: V tile -> LDS, fused db4 DWT ----
    __syncthreads();                 // all waves done reading As/Bs
    #pragma unroll
    for (int mt = 0; mt < 4; ++mt)
        #pragma unroll
        for (int nt = 0; nt < 4; ++nt)
            #pragma unroll
            for (int reg = 0; reg < 4; ++reg)
                Cs[(wm + mt * 16 + quad * 4 + reg) * 134 + wn + nt * 16 + l15] =
                    f2bf(acc[mt][nt][reg]);
    __syncthreads();
    const int rl    = tid & 127;                 // local V row (s)
    const int chunk = tid >> 7;                  // t-half 0/1
    const int rg = m0 + rl;
    const int b = rg >> 11, s = rg & 2047;
    const int bh = b * NH + blockIdx.y;          // h == n0>>7 == blockIdx.y
    const short* vr = Cs + rl * 134;
    auto getv = [&](int i) -> float {
        int k = (i < 6) ? (5 - i) : (i < 134) ? (i - 6) : (261 - i);
        return bf2f(vr[k]);
    };
    const int t0 = chunk * 34;
    const int t1 = (chunk == 0) ? 34 : WA;
    float win[8];
    #pragma unroll
    for (int j = 0; j < 8; ++j) win[j] = getv(2 * t0 + j);
    float* oA = outA + ((size_t)bh * S_ + s) * WA;
    for (int t = t0; t < t1; ++t) {
        float lo = 0.f, hi = 0.f;
        #pragma unroll
        for (int j = 0; j < 8; ++j) { lo += win[j] * FLO[j]; hi += win[j] * FHI[j]; }
        oA[t] = lo;                                          // contiguous per thread
        cdt[((size_t)bh * WPAD + t) * S_ + s] = f2bf(hi);    // lane-coalesced over s
        #pragma unroll
        for (int j = 0; j < 6; ++j) win[j] = win[j + 2];
        if (t + 1 < t1) { win[6] = getv(2 * t + 8); win[7] = getv(2 * t + 9); }
    }
    if (chunk == 1) {
        #pragma unroll
        for (int w = WA; w < WPAD; ++w)
            cdt[((size_t)bh * WPAD + w) * S_ + s] =
                (w == 67) ? (short)0x3F80 : (short)0;   // ones row 67 (l), else 0
    }
}

// ---------------- flash attention: out1 = softmax(QK^T) @ cD ----------------
// 128 q-rows/block (32/wave), grid 16x32=512. Single-buffer staging (proven
// vs dbuf/split-K). S^T trick (A=K, B=Q) packs P as b64 into wave-private
// XOR-swizzled LDS. Unnormalized softmax (|s| < ~15, exp2 domain); the l-sum
// comes FREE from the PV MFMA via the ones-row at w=67 (col 67 of j=4 tile).
__global__ __launch_bounds__(256, 2) void attn_kernel(
    const short* __restrict__ Qb, const short* __restrict__ Kb,
    const short* __restrict__ cdt, float* __restrict__ out1)
{
    __shared__ __align__(16) short Ks[64 * 128];      // 16KB, 16 chunks/row
    __shared__ __align__(16) short Ds[WPAD * 64];     // 10KB, 8 chunks/row
    __shared__ __align__(16) short Pt[8 * 1024];      // 16KB, wave-private P
    const int tid  = threadIdx.x;
    const int wv   = tid >> 6;
    const int lane = tid & 63;
    const int l15  = lane & 15;
    const int quad = lane >> 4;
    const int qt = blockIdx.x;           // 0..15 (128 q-rows each)
    const int bh = blockIdx.y;           // 0..31
    const int b = bh >> 3, h = bh & 7;
    const int rxor = l15 & 7;

    // Q fragments from global, once. Lane layout = row l15, k = quad*8+j
    // (identical for A- and B-operands, so they serve as B in S^T = K Q^T).
    short8 aq[2][4];
    #pragma unroll
    for (int n = 0; n < 2; ++n) {
        const short* qrow =
            Qb + ((size_t)bh * S_ + qt * 128 + wv * 32 + n * 16 + l15) * DK;
        #pragma unroll
        for (int s4 = 0; s4 < 4; ++s4)
            aq[n][s4] = *(const short8*)(qrow + s4 * 32 + quad * 8);
    }

    floatx4 O[2][5] = {};                // j=4 tile col 67 accumulates l

    const short* kbase = Kb + (size_t)bh * S_ * DK;
    const int krow = lane >> 4;                    // K staging: 4 rows/issue
    const int kch  = (lane & 15);
    const int drow = lane >> 3;                    // D staging: 8 rows/issue
    const int dch  = (lane & 7) ^ (drow & 7);
    short* ptw = Pt + wv * 2048;                   // this wave's P (2 tiles)

    for (int kt = 0; kt < 32; ++kt) {
        __syncthreads();                 // prior iter done reading Ks/Ds
        #pragma unroll
        for (int i = 0; i < 4; ++i) {    // K tile: 64 rows x 256B, 16 issues
            int ti = wv * 4 + i;
            int r  = ti * 4 + krow;
            int ch = kch ^ (r & 7);
            glds16(Ks + ti * 512, kbase + ((size_t)kt * 64 + r) * DK + ch * 8);
        }
        #pragma unroll
        for (int i = 0; i < 3; ++i) {    // D tile: 80 rows x 128B, 10 issues
            int t = wv + i * 4;
            if (t < 10) {
                int r = t * 8 + drow;
                glds16(Ds + t * 512,
                       cdt + ((size_t)bh * WPAD + r) * S_ + kt * 64 + dch * 8);
            }
        }
        __syncthreads();                 // vmcnt drained -> tiles ready

        // S^T = K Q^T : C col=l15=q-row, row=quad*4+reg=key
        floatx4 sc[2][4] = {};
        #pragma unroll
        for (int s4 = 0; s4 < 4; ++s4) {
            short8 kf[4];
            #pragma unroll
            for (int mt = 0; mt < 4; ++mt) {
                int ch = (s4 * 4 + quad) ^ rxor;
                kf[mt] = *(const short8*)&Ks[(mt * 16 + l15) * 128 + ch * 8];
            }
            #pragma unroll
            for (int n = 0; n < 2; ++n)
                #pragma unroll
                for (int mt = 0; mt < 4; ++mt)
                    sc[n][mt] = __builtin_amdgcn_mfma_f32_16x16x32_bf16(
                        kf[mt], aq[n][s4], sc[n][mt], 0, 0, 0);
        }
        // p = 2^s; 4 regs = 4 consecutive keys of q-row n*16+l15 -> b64 pack
        #pragma unroll
        for (int n = 0; n < 2; ++n) {
            #pragma unroll
            for (int mt = 0; mt < 4; ++mt) {
                short4v pk;
                #pragma unroll
                for (int reg = 0; reg < 4; ++reg)
                    pk[reg] = f2bf_trunc(hexp2(sc[n][mt][reg]));
                int ch = (mt * 2 + (quad >> 1)) ^ rxor;
                *(short4v*)&ptw[n * 1024 + l15 * 64 + ch * 8 + (quad & 1) * 4] = pk;
            }
        }
        // O += P @ cD   (col 67 of j=4 accumulates l via the ones row)
        short8 ap[2][2];
        #pragma unroll
        for (int mt = 0; mt < 2; ++mt)
            #pragma unroll
            for (int ks = 0; ks < 2; ++ks) {
                int ch = (ks * 4 + quad) ^ rxor;
                ap[mt][ks] = *(const short8*)&ptw[mt * 1024 + l15 * 64 + ch * 8];
            }
        #pragma unroll
        for (int j = 0; j < 5; ++j) {
            #pragma unroll
            for (int ks = 0; ks < 2; ++ks) {
                int ch = (ks * 4 + quad) ^ rxor;
                short8 bd = *(const short8*)&Ds[(j * 16 + l15) * 64 + ch * 8];
                #pragma unroll
                for (int mt = 0; mt < 2; ++mt)
                    O[mt][j] = __builtin_amdgcn_mfma_f32_16x16x32_bf16(
                        ap[mt][ks], bd, O[mt][j], 0, 0, 0);
            }
        }
    }
    // l(r) sits at element (row r, col 67) = lane (r>>2)*16+3, reg r&3 of j=4.
    float rl[2][4];
    #pragma unroll
    for (int mt = 0; mt < 2; ++mt)
        #pragma unroll
        for (int reg = 0; reg < 4; ++reg)
            rl[mt][reg] = 1.0f / __shfl(O[mt][4][reg], (quad << 4) | 3, 64);
    // epilogue: out1[b][q][h*67+w] = O * (1/l)   (w >= 67 dropped)
    #pragma unroll
    for (int mt = 0; mt < 2; ++mt)
        #pragma unroll
        for (int j = 0; j < 5; ++j) {
            int w = j * 16 + l15;
            if (w < WA) {
                #pragma unroll
                for (int reg = 0; reg < 4; ++reg) {
                    int qrow_g = qt * 128 + wv * 32 + mt * 16 + quad * 4 + reg;
                    out1[((size_t)(b * S_ + qrow_g)) * (NH * WA) + h * WA + w] =
                        O[mt][j][reg] * rl[mt][reg];
                }
            }
        }
}

extern "C" void kernel_launch(void* const* d_in, const int* in_sizes, int n_in,
                              void* d_out, int out_size, void* d_ws, size_t ws_size,
                              hipStream_t stream)
{
    const float* x  = (const float*)d_in[0];
    const float* Wq = (const float*)d_in[1];
    const float* Wk = (const float*)d_in[2];
    const float* Wv = (const float*)d_in[3];
    float* out = (float*)d_out;

    const size_t x_elems   = (size_t)B_ * S_ * HD;           // 8,388,608
    const size_t w_elems   = (size_t)HD * HD;                // 1,048,576
    const size_t qkv_elems = (size_t)B_ * NH * S_ * DK;      // 8,388,608
    short* xb  = (short*)d_ws;
    short* Wb  = xb + x_elems;                               // 3 concatenated
    short* Qb  = Wb + 3 * w_elems;
    short* Kb  = Qb + qkv_elems;
    short* cdt = Kb + qkv_elems;                             // (b,h,w=80,s) bf16
    float* out1 = out;                                       // (B,S,536)
    float* out2 = out + (size_t)B_ * S_ * NH * WA;           // (B,H,S,67)

    cvt_all<<<dim3(5632), 256, 0, stream>>>(x, Wq, Wk, Wv, xb, Wb);
    qkv_gemm<<<dim3(64, 8, 3), 256, 0, stream>>>(xb, Wb, Qb, Kb, out2, cdt);
    attn_kernel<<<dim3(16, 32), 256, 0, stream>>>(Qb, Kb, cdt, out1);
}